// Round 7
// baseline (324.171 us; speedup 1.0000x reference)
//
#include <hip/hip_runtime.h>

// out[b,s,k] = sum_n x[b,s,n] * W[k,n] + bias[k]
// W[k,n] = (W_q[k,n] - zeros[k,n/64]) * scales[k,n/64] * scale2[k] * mask[k,n]
// M = B*S = 8192 (rows of x), N = 4096 (reduction), K = 4096 (out features).

#define M_DIM 8192
#define N_DIM 4096
#define K_DIM 4096
#define NT 64  // K-tiles of BK=64

typedef __bf16 bf16;
typedef __attribute__((ext_vector_type(8))) bf16 bf16x8;
typedef __attribute__((ext_vector_type(16))) float f32x16;
typedef __attribute__((ext_vector_type(4))) float f32x4v;   // for nontemporal builtins
typedef __attribute__((ext_vector_type(4))) int   i32x4v;

// ---------------------------------------------------------------- pre-pass 1
__global__ __launch_bounds__(256) void cvt_x_kernel(const float* __restrict__ x,
                                                    bf16* __restrict__ xb) {
  const long total = (long)M_DIM * N_DIM / 8;
  const long stride = (long)gridDim.x * blockDim.x;
  for (long t = (long)blockIdx.x * blockDim.x + threadIdx.x; t < total; t += stride) {
    const long e = t * 8;
    const f32x4v v0 = __builtin_nontemporal_load(reinterpret_cast<const f32x4v*>(x + e));
    const f32x4v v1 = __builtin_nontemporal_load(reinterpret_cast<const f32x4v*>(x + e + 4));
    bf16x8 o;
    o[0] = (bf16)v0[0]; o[1] = (bf16)v0[1]; o[2] = (bf16)v0[2]; o[3] = (bf16)v0[3];
    o[4] = (bf16)v1[0]; o[5] = (bf16)v1[1]; o[6] = (bf16)v1[2]; o[7] = (bf16)v1[3];
    *reinterpret_cast<bf16x8*>(xb + e) = o;  // xb stays cached (GEMM re-reads)
  }
}

// ---------------------------------------------------------------- pre-pass 2
__global__ __launch_bounds__(256) void deq_w_kernel(const int* __restrict__ Wq,
                                                    const float* __restrict__ scales,
                                                    const float* __restrict__ zeros,
                                                    const int* __restrict__ mask,
                                                    const float* __restrict__ scale2,
                                                    bf16* __restrict__ wb) {
  const int total = K_DIM * (N_DIM / 8);
  const int stride = gridDim.x * blockDim.x;
  for (int t = blockIdx.x * blockDim.x + threadIdx.x; t < total; t += stride) {
    const int k = t >> 9;
    const int n0 = (t & 511) << 3;
    const int g = n0 >> 6;
    const float s = scales[(k << 6) + g] * scale2[k];
    const float z = zeros[(k << 6) + g];
    const long base = (long)k * N_DIM + n0;
    const i32x4v q0 = __builtin_nontemporal_load(reinterpret_cast<const i32x4v*>(Wq + base));
    const i32x4v q1 = __builtin_nontemporal_load(reinterpret_cast<const i32x4v*>(Wq + base + 4));
    const i32x4v m0 = __builtin_nontemporal_load(reinterpret_cast<const i32x4v*>(mask + base));
    const i32x4v m1 = __builtin_nontemporal_load(reinterpret_cast<const i32x4v*>(mask + base + 4));
    bf16x8 o;
    o[0] = (bf16)(((float)q0[0] - z) * s * (float)m0[0]);
    o[1] = (bf16)(((float)q0[1] - z) * s * (float)m0[1]);
    o[2] = (bf16)(((float)q0[2] - z) * s * (float)m0[2]);
    o[3] = (bf16)(((float)q0[3] - z) * s * (float)m0[3]);
    o[4] = (bf16)(((float)q1[0] - z) * s * (float)m1[0]);
    o[5] = (bf16)(((float)q1[1] - z) * s * (float)m1[1]);
    o[6] = (bf16)(((float)q1[2] - z) * s * (float)m1[2]);
    o[7] = (bf16)(((float)q1[3] - z) * s * (float)m1[3]);
    *reinterpret_cast<bf16x8*>(wb + base) = o;  // wb stays cached
  }
}

// ---------------------------------------------------------------- GEMM
// Round-5 skeleton (verified ledger, 0 bank conflicts) with 32x32x16 MFMA
// (2382 vs 2075 TF pipe, half the issue slots; mappings HW-verified round 4)
// and non-temporal epilogue stores (keep xb/wb L3-resident).
//
// 256x256 tile, BK=64, 8 waves (2M x 4N), 4-phase-per-K-tile schedule,
// double-buffered LDS (128 KiB), one counted vmcnt(6) per K-tile.
//
// LDS per buffer (32768 elem): A [0,16384) = 256 rows x 64 cols bf16,
// B [16384,32768). Row = 128 B; swizzle: (row, slot 0..7 of 8 bf16) at byte
// row*128 + x*16, x = slot ^ (row&7). global_load_lds writes linearly ->
// per-lane GLOBAL source pre-permuted by the same involution.
//
// Half-tiles (quadrant-row unions, each read in exactly ONE phase):
//   A-half h = rows {wr*128 + [h*64, +64)}   (mb in {2h, 2h+1})
//   B-half h = rows {wc*64  + [h*32, +32)}   (nb = h)
// Phase reads: ph0: Ah0+Bh0; ph1: Bh1; ph2: Ah1; ph3: none.
// Stages:      ph0: Ah1(t+1)->other; ph1: Ah0(t+2)->cur; ph2: Bh0(t+2)->cur;
//              ph3: Bh1(t+2)->cur; vmcnt(6) at ph3 retires through Ah1(t+1).
__device__ inline void gload16(const bf16* g, bf16* l) {
  __builtin_amdgcn_global_load_lds(
      (const __attribute__((address_space(1))) void*)g,
      (__attribute__((address_space(3))) void*)l, 16, 0, 0);
}

#define BARRIER asm volatile("s_barrier" ::: "memory")
#define LGKM0   asm volatile("s_waitcnt lgkmcnt(0)" ::: "memory")
#define VM6     asm volatile("s_waitcnt vmcnt(6)" ::: "memory")
#define VM0     asm volatile("s_waitcnt vmcnt(0)" ::: "memory")
#define SBAR    __builtin_amdgcn_sched_barrier(0)

__global__ __launch_bounds__(512, 2) void gemm_kernel(const bf16* __restrict__ xb,
                                                      const bf16* __restrict__ wb,
                                                      const float* __restrict__ bias,
                                                      float* __restrict__ out) {
  __shared__ bf16 lds[65536];  // 128 KiB: 2 buffers x (16K A + 16K B) elements

  const int tid = threadIdx.x;
  const int lane = tid & 63;
  const int w = tid >> 6;
  const int wr = w >> 2;  // 0..1  (M half, 128 rows)
  const int wc = w & 3;   // 0..3  (N quarter, 64 cols)

  // T1: bijective XCD swizzle; nwg = 512 % 8 == 0.
  const int gid = blockIdx.x;
  const int swz = ((gid & 7) << 6) | (gid >> 3);
  const int bm = swz & 31;  // 32 M-tiles
  const int bk = swz >> 5;  // 16 K-tiles
  const long m0 = (long)bm * 256;
  const long k0 = (long)bk * 256;

  // ---- staging source decode (inverse swizzle), per-thread constants.
  const int browA = tid >> 3;                      // 0..63
  const int slotA = (tid & 7) ^ (browA & 7);
  const bf16* baseA = xb + (m0 + browA) * N_DIM + slotA * 8;
  const int u = tid & 255;
  const int wcb = tid >> 8;                        // 0..1
  const int browB = u >> 3;                        // 0..31
  const int slotB = (u & 7) ^ (browB & 7);
  const bf16* baseB = wb + (k0 + wcb * 64 + browB) * N_DIM + slotB * 8;

  // ---- ds_read fragment bases (32x32x16). Lane: row += (lane&31);
  // k-window for MFMA kk = kk*16 + (lane>>5)*8 -> slot = kk*2 + (lane>>5);
  // x = slot ^ (row&7), row&7 == lane&7 (row offsets are multiples of 32).
  const int ln31 = lane & 31;
  int aoffk[4], boffk[4];
#pragma unroll
  for (int kk = 0; kk < 4; ++kk) {
    const int x = (kk * 2 + (lane >> 5)) ^ (lane & 7);
    aoffk[kk] = (wr * 128 + ln31) * 64 + x * 8;           // + mb*2048
    boffk[kk] = 16384 + (wc * 64 + ln31) * 64 + x * 8;    // + nb*2048
  }

  f32x16 acc[4][2] = {};
  bf16x8 af[2][4], bfA[4], bfB[4];

  auto STA = [&](int tt, int bsel, int h) {  // stage A-half h of tile tt
    const bf16* s = baseA + (long)(h * 64) * N_DIM + tt * 64;
    bf16* d = lds + bsel * 32768 + h * 4096 + (tid << 3);
    gload16(s, d);
    gload16(s + (long)128 * N_DIM, d + 8192);
  };
  auto STB = [&](int tt, int bsel, int h) {  // stage B-half h of tile tt
    const bf16* s = baseB + (long)(h * 32) * N_DIM + tt * 64;
    bf16* d = lds + bsel * 32768 + 16384 + wcb * 4096 + h * 2048 + (u << 3);
    gload16(s, d);
    gload16(s + (long)128 * N_DIM, d + 8192);
  };
  auto LDA = [&](int cb, int mh) {
#pragma unroll
    for (int mb = 0; mb < 2; ++mb)
#pragma unroll
      for (int kk = 0; kk < 4; ++kk)
        af[mb][kk] = *reinterpret_cast<const bf16x8*>(
            lds + cb + aoffk[kk] + (mh * 2 + mb) * 2048);
  };
  auto LDB = [&](bf16x8* bf, int cb, int nh) {
#pragma unroll
    for (int kk = 0; kk < 4; ++kk)
      bf[kk] = *reinterpret_cast<const bf16x8*>(
          lds + cb + boffk[kk] + nh * 2048);
  };
  auto MFMA8 = [&](bf16x8* bf, int mh, int nh) {
    __builtin_amdgcn_s_setprio(1);
#pragma unroll
    for (int kk = 0; kk < 4; ++kk)
#pragma unroll
      for (int mb = 0; mb < 2; ++mb)
        acc[mh * 2 + mb][nh] = __builtin_amdgcn_mfma_f32_32x32x16_bf16(
            af[mb][kk], bf[kk], acc[mh * 2 + mb][nh], 0, 0, 0);
    __builtin_amdgcn_s_setprio(0);
  };

  // Prologue (FIFO order = consumption order): tile0 {Ah0,Bh0,Bh1,Ah1},
  // tile1 {Ah0,Bh0,Bh1}. 14 loads; vmcnt(6) retires tile0's 8.
  STA(0, 0, 0); STB(0, 0, 0); STB(0, 0, 1); STA(0, 0, 1);
  STA(1, 1, 0); STB(1, 1, 0); STB(1, 1, 1);
  VM6; BARRIER;

  auto TILE = [&](int t, int c) {
    const int cb = c * 32768;
    // ph0: read Ah0 + Bh0; stage Ah1(t+1) -> other buf
    LDA(cb, 0); LDB(bfA, cb, 0);
    if (t + 1 < NT) STA(t + 1, c ^ 1, 1);
    asm volatile("s_waitcnt lgkmcnt(8)" ::: "memory");
    BARRIER; LGKM0; SBAR;
    MFMA8(bfA, 0, 0); SBAR; BARRIER;
    // ph1: read Bh1; stage Ah0(t+2) -> cur buf (region dead since ph0)
    LDB(bfB, cb, 1);
    if (t + 2 < NT) STA(t + 2, c, 0);
    BARRIER; LGKM0; SBAR;
    MFMA8(bfB, 0, 1); SBAR; BARRIER;
    // ph2: read Ah1; stage Bh0(t+2) -> cur (dead since ph0)
    LDA(cb, 1);
    if (t + 2 < NT) STB(t + 2, c, 0);
    BARRIER; LGKM0; SBAR;
    MFMA8(bfA, 1, 0); SBAR; BARRIER;
    // ph3: no reads; stage Bh1(t+2) -> cur (dead since ph1); counted wait
    if (t + 2 < NT) STB(t + 2, c, 1);
    if (t < NT - 2) { VM6; } else { VM0; }
    BARRIER; LGKM0; SBAR;
    MFMA8(bfB, 1, 1); SBAR; BARRIER;
  };

  for (int tp = 0; tp < NT / 2; ++tp) {
    TILE(2 * tp, 0);
    TILE(2 * tp + 1, 1);
  }

  // Epilogue. 32x32 C/D layout (m74/m101, HW-verified round 4):
  // col = lane&31, row = (reg&3) + 8*(reg>>2) + 4*(lane>>5).
  // Non-temporal stores: don't evict xb/wb from L3.
  const int ocol0 = (int)k0 + wc * 64 + ln31;
  const int orow0 = (int)m0 + wr * 128 + 4 * (lane >> 5);
#pragma unroll
  for (int nb = 0; nb < 2; ++nb) {
    const float bv = bias[ocol0 + nb * 32];
#pragma unroll
    for (int mb = 0; mb < 4; ++mb) {
#pragma unroll
      for (int r = 0; r < 16; ++r) {
        const int row = orow0 + mb * 32 + (r & 3) + 8 * (r >> 2);
        __builtin_nontemporal_store(acc[mb][nb][r] + bv,
                                    &out[(long)row * K_DIM + ocol0 + nb * 32]);
      }
    }
  }
}

// ---------------------------------------------------------------- launch
extern "C" void kernel_launch(void* const* d_in, const int* in_sizes, int n_in,
                              void* d_out, int out_size, void* d_ws, size_t ws_size,
                              hipStream_t stream) {
  const float* x      = (const float*)d_in[0];
  const int*   Wq     = (const int*)d_in[1];
  const float* scales = (const float*)d_in[2];
  const float* zeros  = (const float*)d_in[3];
  const int*   mask   = (const int*)d_in[4];
  const float* scale2 = (const float*)d_in[5];
  const float* bias   = (const float*)d_in[6];
  float* out = (float*)d_out;

  bf16* xb = (bf16*)d_ws;
  bf16* wb = (bf16*)((char*)d_ws + (size_t)M_DIM * N_DIM * 2);

  cvt_x_kernel<<<2048, 256, 0, stream>>>(x, xb);
  deq_w_kernel<<<2048, 256, 0, stream>>>(Wq, scales, zeros, mask, scale2, wb);

  // Grid: (M/256) * (K/256) = 32 * 16 = 512 blocks, 512 threads.
  gemm_kernel<<<512, 512, 0, stream>>>(xb, wb, bias, out);
}

// Round 8
// 287.071 us; speedup vs baseline: 1.1292x; 1.1292x over previous
//
#include <hip/hip_runtime.h>

// out[b,s,k] = sum_n x[b,s,n] * W[k,n] + bias[k]
// W[k,n] = (W_q[k,n] - zeros[k,n/64]) * scales[k,n/64] * scale2[k] * mask[k,n]
// M = B*S = 8192 (rows of x), N = 4096 (reduction), K = 4096 (out features).

#define M_DIM 8192
#define N_DIM 4096
#define K_DIM 4096
#define NT 64  // K-tiles of BK=64

typedef __bf16 bf16;
typedef __attribute__((ext_vector_type(8))) bf16 bf16x8;
typedef __attribute__((ext_vector_type(4))) float f32x4;
typedef __attribute__((ext_vector_type(4))) float f32x4v;   // nontemporal builtins
typedef __attribute__((ext_vector_type(4))) int   i32x4v;

// ---------------------------------------------------------------- pre-pass 1
__global__ __launch_bounds__(256) void cvt_x_kernel(const float* __restrict__ x,
                                                    bf16* __restrict__ xb) {
  const long total = (long)M_DIM * N_DIM / 8;
  const long stride = (long)gridDim.x * blockDim.x;
  for (long t = (long)blockIdx.x * blockDim.x + threadIdx.x; t < total; t += stride) {
    const long e = t * 8;
    const f32x4v v0 = __builtin_nontemporal_load(reinterpret_cast<const f32x4v*>(x + e));
    const f32x4v v1 = __builtin_nontemporal_load(reinterpret_cast<const f32x4v*>(x + e + 4));
    bf16x8 o;
    o[0] = (bf16)v0[0]; o[1] = (bf16)v0[1]; o[2] = (bf16)v0[2]; o[3] = (bf16)v0[3];
    o[4] = (bf16)v1[0]; o[5] = (bf16)v1[1]; o[6] = (bf16)v1[2]; o[7] = (bf16)v1[3];
    *reinterpret_cast<bf16x8*>(xb + e) = o;  // xb stays cached (GEMM re-reads)
  }
}

// ---------------------------------------------------------------- pre-pass 2
__global__ __launch_bounds__(256) void deq_w_kernel(const int* __restrict__ Wq,
                                                    const float* __restrict__ scales,
                                                    const float* __restrict__ zeros,
                                                    const int* __restrict__ mask,
                                                    const float* __restrict__ scale2,
                                                    bf16* __restrict__ wb) {
  const int total = K_DIM * (N_DIM / 8);
  const int stride = gridDim.x * blockDim.x;
  for (int t = blockIdx.x * blockDim.x + threadIdx.x; t < total; t += stride) {
    const int k = t >> 9;
    const int n0 = (t & 511) << 3;
    const int g = n0 >> 6;
    const float s = scales[(k << 6) + g] * scale2[k];
    const float z = zeros[(k << 6) + g];
    const long base = (long)k * N_DIM + n0;
    const i32x4v q0 = __builtin_nontemporal_load(reinterpret_cast<const i32x4v*>(Wq + base));
    const i32x4v q1 = __builtin_nontemporal_load(reinterpret_cast<const i32x4v*>(Wq + base + 4));
    const i32x4v m0 = __builtin_nontemporal_load(reinterpret_cast<const i32x4v*>(mask + base));
    const i32x4v m1 = __builtin_nontemporal_load(reinterpret_cast<const i32x4v*>(mask + base + 4));
    bf16x8 o;
    o[0] = (bf16)(((float)q0[0] - z) * s * (float)m0[0]);
    o[1] = (bf16)(((float)q0[1] - z) * s * (float)m0[1]);
    o[2] = (bf16)(((float)q0[2] - z) * s * (float)m0[2]);
    o[3] = (bf16)(((float)q0[3] - z) * s * (float)m0[3]);
    o[4] = (bf16)(((float)q1[0] - z) * s * (float)m1[0]);
    o[5] = (bf16)(((float)q1[1] - z) * s * (float)m1[1]);
    o[6] = (bf16)(((float)q1[2] - z) * s * (float)m1[2]);
    o[7] = (bf16)(((float)q1[3] - z) * s * (float)m1[3]);
    *reinterpret_cast<bf16x8*>(wb + base) = o;  // wb stays cached
  }
}

// ---------------------------------------------------------------- GEMM
// Round-5 skeleton verbatim (16x16x32 MFMA, verified ledger, 0 bank
// conflicts) with ONE change: XCD mapping now keeps the A-panel L2-resident
// (each XCD owns 4 bm x all 16 bk; 16 consecutive blocks share bm -> the
// 2.1 MB A-panel lives in the XCD's 4 MB L2; B relies on L3 with all XCDs
// streaming the same bk order concurrently). Plus nt epilogue stores.
//
// 256x256 tile, BK=64, 8 waves (2M x 4N), 4-phase-per-K-tile schedule,
// double-buffered LDS (128 KiB), one counted vmcnt(6) per K-tile.
//
// LDS per buffer (32768 elem): A [0,16384) = 256 rows x 64 cols bf16,
// B [16384,32768). Row = 128 B; swizzle: (row, slot 0..7 of 8 bf16) at byte
// row*128 + x*16, x = slot ^ (row&7). global_load_lds writes linearly ->
// per-lane GLOBAL source pre-permuted by the same involution.
//
// Half-tiles (quadrant-row unions, each read in exactly ONE phase):
//   A-half h = rows {wr*128 + [h*64, +64)}; B-half h = rows {wc*64 + [h*32, +32)}
// Phase reads: ph0: Ah0+Bh0; ph1: Bh1; ph2: Ah1; ph3: none.
// Stages:      ph0: Ah1(t+1)->other; ph1: Ah0(t+2)->cur; ph2: Bh0(t+2)->cur;
//              ph3: Bh1(t+2)->cur; vmcnt(6) at ph3 retires through Ah1(t+1).
__device__ inline void gload16(const bf16* g, bf16* l) {
  __builtin_amdgcn_global_load_lds(
      (const __attribute__((address_space(1))) void*)g,
      (__attribute__((address_space(3))) void*)l, 16, 0, 0);
}

#define BARRIER asm volatile("s_barrier" ::: "memory")
#define LGKM0   asm volatile("s_waitcnt lgkmcnt(0)" ::: "memory")
#define VM6     asm volatile("s_waitcnt vmcnt(6)" ::: "memory")
#define VM0     asm volatile("s_waitcnt vmcnt(0)" ::: "memory")
#define SBAR    __builtin_amdgcn_sched_barrier(0)

__global__ __launch_bounds__(512, 2) void gemm_kernel(const bf16* __restrict__ xb,
                                                      const bf16* __restrict__ wb,
                                                      const float* __restrict__ bias,
                                                      float* __restrict__ out) {
  __shared__ bf16 lds[65536];  // 128 KiB: 2 buffers x (16K A + 16K B) elements

  const int tid = threadIdx.x;
  const int lane = tid & 63;
  const int w = tid >> 6;
  const int wr = w >> 2;  // 0..1  (M half, 128 rows)
  const int wc = w & 3;   // 0..3  (N quarter, 64 cols)

  // XCD mapping: xcd = gid&7 owns bm in [xcd*4, xcd*4+4), all bk.
  // 16 consecutive blocks on one XCD share bm -> A-panel L2-resident.
  const int gid = blockIdx.x;
  const int idx = gid >> 3;                 // 0..63
  const int bm = (gid & 7) * 4 + (idx >> 4);  // 32 M-tiles
  const int bk = idx & 15;                    // 16 K-tiles
  const long m0 = (long)bm * 256;
  const long k0 = (long)bk * 256;

  // ---- staging source decode (inverse swizzle), per-thread constants.
  const int browA = tid >> 3;                      // 0..63
  const int slotA = (tid & 7) ^ (browA & 7);
  const bf16* baseA = xb + (m0 + browA) * N_DIM + slotA * 8;
  const int u = tid & 255;
  const int wcb = tid >> 8;                        // 0..1
  const int browB = u >> 3;                        // 0..31
  const int slotB = (u & 7) ^ (browB & 7);
  const bf16* baseB = wb + (k0 + wcb * 64 + browB) * N_DIM + slotB * 8;

  // ---- ds_read fragment bases. Lane: row += (lane&15); k-slot = kk*4+(lane>>4);
  // x = (kk*4 + (lane>>4)) ^ (lane&7)  [row&7 == lane&7 for all frag rows].
  const int ln15 = lane & 15;
  const int x0 = (lane >> 4) ^ (lane & 7);
  int aoffk[2], boffk[2];
#pragma unroll
  for (int kk = 0; kk < 2; ++kk) {
    const int x = x0 ^ (kk << 2);
    aoffk[kk] = (wr * 128 + ln15) * 64 + x * 8;
    boffk[kk] = 16384 + (wc * 64 + ln15) * 64 + x * 8;
  }

  f32x4 acc[8][4] = {};
  bf16x8 af[4][2], bfA[2][2], bfB[2][2];

  auto STA = [&](int tt, int bsel, int h) {  // stage A-half h of tile tt
    const bf16* s = baseA + (long)(h * 64) * N_DIM + tt * 64;
    bf16* d = lds + bsel * 32768 + h * 4096 + (tid << 3);
    gload16(s, d);
    gload16(s + (long)128 * N_DIM, d + 8192);
  };
  auto STB = [&](int tt, int bsel, int h) {  // stage B-half h of tile tt
    const bf16* s = baseB + (long)(h * 32) * N_DIM + tt * 64;
    bf16* d = lds + bsel * 32768 + 16384 + wcb * 4096 + h * 2048 + (u << 3);
    gload16(s, d);
    gload16(s + (long)128 * N_DIM, d + 8192);
  };
  auto LDA = [&](int cb, int mh) {
#pragma unroll
    for (int mf = 0; mf < 4; ++mf)
#pragma unroll
      for (int kk = 0; kk < 2; ++kk)
        af[mf][kk] = *reinterpret_cast<const bf16x8*>(
            lds + cb + aoffk[kk] + mh * 4096 + mf * 1024);
  };
  auto LDB = [&](bf16x8 (*bf)[2], int cb, int nh) {
#pragma unroll
    for (int nf = 0; nf < 2; ++nf)
#pragma unroll
      for (int kk = 0; kk < 2; ++kk)
        bf[nf][kk] = *reinterpret_cast<const bf16x8*>(
            lds + cb + boffk[kk] + nh * 2048 + nf * 1024);
  };
  auto MFMA_Q = [&](bf16x8 (*bf)[2], int mh, int nh) {
    __builtin_amdgcn_s_setprio(1);
#pragma unroll
    for (int kk = 0; kk < 2; ++kk)
#pragma unroll
      for (int mf = 0; mf < 4; ++mf)
#pragma unroll
        for (int nf = 0; nf < 2; ++nf)
          acc[mh * 4 + mf][nh * 2 + nf] = __builtin_amdgcn_mfma_f32_16x16x32_bf16(
              af[mf][kk], bf[nf][kk], acc[mh * 4 + mf][nh * 2 + nf], 0, 0, 0);
    __builtin_amdgcn_s_setprio(0);
  };

  // Prologue (FIFO order = consumption order): tile0 {Ah0,Bh0,Bh1,Ah1},
  // tile1 {Ah0,Bh0,Bh1}. 14 loads; vmcnt(6) retires tile0's 8.
  STA(0, 0, 0); STB(0, 0, 0); STB(0, 0, 1); STA(0, 0, 1);
  STA(1, 1, 0); STB(1, 1, 0); STB(1, 1, 1);
  VM6; BARRIER;

  auto TILE = [&](int t, int c) {
    const int cb = c * 32768;
    // ph0: read Ah0 + Bh0; stage Ah1(t+1) -> other buf
    LDA(cb, 0); LDB(bfA, cb, 0);
    if (t + 1 < NT) STA(t + 1, c ^ 1, 1);
    asm volatile("s_waitcnt lgkmcnt(8)" ::: "memory");
    BARRIER; LGKM0; SBAR;
    MFMA_Q(bfA, 0, 0); SBAR; BARRIER;
    // ph1: read Bh1; stage Ah0(t+2) -> cur buf (region dead since ph0)
    LDB(bfB, cb, 1);
    if (t + 2 < NT) STA(t + 2, c, 0);
    BARRIER; LGKM0; SBAR;
    MFMA_Q(bfB, 0, 1); SBAR; BARRIER;
    // ph2: read Ah1 (reuse af regs); stage Bh0(t+2) -> cur (dead since ph0)
    LDA(cb, 1);
    if (t + 2 < NT) STB(t + 2, c, 0);
    BARRIER; LGKM0; SBAR;
    MFMA_Q(bfA, 1, 0); SBAR; BARRIER;
    // ph3: no reads; stage Bh1(t+2) -> cur (dead since ph1); counted wait
    if (t + 2 < NT) STB(t + 2, c, 1);
    if (t < NT - 2) { VM6; } else { VM0; }
    BARRIER; LGKM0; SBAR;
    MFMA_Q(bfB, 1, 1); SBAR; BARRIER;
  };

  for (int tp = 0; tp < NT / 2; ++tp) {
    TILE(2 * tp, 0);
    TILE(2 * tp + 1, 1);
  }

  // Epilogue. C/D: col = lane&15 (K-dim), row = (lane>>4)*4 + r (M-dim).
  // Non-temporal stores: out is write-once, keep xb/wb cached instead.
  const int ocol0 = (int)k0 + wc * 64 + ln15;
  const int orow0 = (int)m0 + wr * 128 + (lane >> 4) * 4;
#pragma unroll
  for (int ni = 0; ni < 4; ++ni) {
    const float bv = bias[ocol0 + ni * 16];
#pragma unroll
    for (int mi = 0; mi < 8; ++mi)
#pragma unroll
      for (int r = 0; r < 4; ++r)
        __builtin_nontemporal_store(
            acc[mi][ni][r] + bv,
            &out[(long)(orow0 + mi * 16 + r) * K_DIM + ocol0 + ni * 16]);
  }
}

// ---------------------------------------------------------------- launch
extern "C" void kernel_launch(void* const* d_in, const int* in_sizes, int n_in,
                              void* d_out, int out_size, void* d_ws, size_t ws_size,
                              hipStream_t stream) {
  const float* x      = (const float*)d_in[0];
  const int*   Wq     = (const int*)d_in[1];
  const float* scales = (const float*)d_in[2];
  const float* zeros  = (const float*)d_in[3];
  const int*   mask   = (const int*)d_in[4];
  const float* scale2 = (const float*)d_in[5];
  const float* bias   = (const float*)d_in[6];
  float* out = (float*)d_out;

  bf16* xb = (bf16*)d_ws;
  bf16* wb = (bf16*)((char*)d_ws + (size_t)M_DIM * N_DIM * 2);

  cvt_x_kernel<<<2048, 256, 0, stream>>>(x, xb);
  deq_w_kernel<<<2048, 256, 0, stream>>>(Wq, scales, zeros, mask, scale2, wb);

  // Grid: (M/256) * (K/256) = 32 * 16 = 512 blocks, 512 threads.
  gemm_kernel<<<512, 512, 0, stream>>>(xb, wb, bias, out);
}

// Round 9
// 287.013 us; speedup vs baseline: 1.1295x; 1.0002x over previous
//
#include <hip/hip_runtime.h>

// out[b,s,k] = sum_n x[b,s,n] * W[k,n] + bias[k]
// W[k,n] = (W_q[k,n] - zeros[k,n/64]) * scales[k,n/64] * scale2[k] * mask[k,n]
// M = B*S = 8192 (rows of x), N = 4096 (reduction), K = 4096 (out features).

#define M_DIM 8192
#define N_DIM 4096
#define K_DIM 4096
#define NT 64  // K-tiles of BK=64

typedef __bf16 bf16;
typedef __attribute__((ext_vector_type(8))) bf16 bf16x8;
typedef __attribute__((ext_vector_type(4))) float f32x4;
typedef __attribute__((ext_vector_type(4))) float f32x4v;   // nontemporal builtins
typedef __attribute__((ext_vector_type(4))) int   i32x4v;

// ---------------------------------------------------------------- pre-pass 1
__global__ __launch_bounds__(256) void cvt_x_kernel(const float* __restrict__ x,
                                                    bf16* __restrict__ xb) {
  const long total = (long)M_DIM * N_DIM / 8;
  const long stride = (long)gridDim.x * blockDim.x;
  for (long t = (long)blockIdx.x * blockDim.x + threadIdx.x; t < total; t += stride) {
    const long e = t * 8;
    const f32x4v v0 = __builtin_nontemporal_load(reinterpret_cast<const f32x4v*>(x + e));
    const f32x4v v1 = __builtin_nontemporal_load(reinterpret_cast<const f32x4v*>(x + e + 4));
    bf16x8 o;
    o[0] = (bf16)v0[0]; o[1] = (bf16)v0[1]; o[2] = (bf16)v0[2]; o[3] = (bf16)v0[3];
    o[4] = (bf16)v1[0]; o[5] = (bf16)v1[1]; o[6] = (bf16)v1[2]; o[7] = (bf16)v1[3];
    *reinterpret_cast<bf16x8*>(xb + e) = o;  // xb stays cached (GEMM re-reads)
  }
}

// ---------------------------------------------------------------- pre-pass 2
__global__ __launch_bounds__(256) void deq_w_kernel(const int* __restrict__ Wq,
                                                    const float* __restrict__ scales,
                                                    const float* __restrict__ zeros,
                                                    const int* __restrict__ mask,
                                                    const float* __restrict__ scale2,
                                                    bf16* __restrict__ wb) {
  const int total = K_DIM * (N_DIM / 8);
  const int stride = gridDim.x * blockDim.x;
  for (int t = blockIdx.x * blockDim.x + threadIdx.x; t < total; t += stride) {
    const int k = t >> 9;
    const int n0 = (t & 511) << 3;
    const int g = n0 >> 6;
    const float s = scales[(k << 6) + g] * scale2[k];
    const float z = zeros[(k << 6) + g];
    const long base = (long)k * N_DIM + n0;
    const i32x4v q0 = __builtin_nontemporal_load(reinterpret_cast<const i32x4v*>(Wq + base));
    const i32x4v q1 = __builtin_nontemporal_load(reinterpret_cast<const i32x4v*>(Wq + base + 4));
    const i32x4v m0 = __builtin_nontemporal_load(reinterpret_cast<const i32x4v*>(mask + base));
    const i32x4v m1 = __builtin_nontemporal_load(reinterpret_cast<const i32x4v*>(mask + base + 4));
    bf16x8 o;
    o[0] = (bf16)(((float)q0[0] - z) * s * (float)m0[0]);
    o[1] = (bf16)(((float)q0[1] - z) * s * (float)m0[1]);
    o[2] = (bf16)(((float)q0[2] - z) * s * (float)m0[2]);
    o[3] = (bf16)(((float)q0[3] - z) * s * (float)m0[3]);
    o[4] = (bf16)(((float)q1[0] - z) * s * (float)m1[0]);
    o[5] = (bf16)(((float)q1[1] - z) * s * (float)m1[1]);
    o[6] = (bf16)(((float)q1[2] - z) * s * (float)m1[2]);
    o[7] = (bf16)(((float)q1[3] - z) * s * (float)m1[3]);
    *reinterpret_cast<bf16x8*>(wb + base) = o;  // wb stays cached
  }
}

// ---------------------------------------------------------------- GEMM
// Round-8 skeleton (16x16x32, 0 conflicts, A-panel-resident XCD mapping,
// counted vmcnt(6)) + register frag double-buffering: each phase's MFMA
// consumes frags loaded during the PREVIOUS phase's MFMA cluster, so ds_read
// latency is off the critical path.
//
// Frag sets:  afH0 (Ah0: used ph0,ph1; prefetched at ph3 of prev tile)
//             afH1 (Ah1: used ph2,ph3; loaded during ph1)
//             bfA  (Bh0: used ph0,ph2; prefetched at ph3 of prev tile)
//             bfB  (Bh1: used ph1,ph3; loaded during ph0)
// Hazards (verified): every region's reads drain at an LGKM0 >=1 barrier
// before the stage-issue overwriting it; ph3's next-tile prefetch follows
// VM6 (retires exactly through Ah1(t+1)) + barrier.
__device__ inline void gload16(const bf16* g, bf16* l) {
  __builtin_amdgcn_global_load_lds(
      (const __attribute__((address_space(1))) void*)g,
      (__attribute__((address_space(3))) void*)l, 16, 0, 0);
}

#define BARRIER asm volatile("s_barrier" ::: "memory")
#define LGKM0   asm volatile("s_waitcnt lgkmcnt(0)" ::: "memory")
#define VM6     asm volatile("s_waitcnt vmcnt(6)" ::: "memory")
#define VM0     asm volatile("s_waitcnt vmcnt(0)" ::: "memory")
#define SBAR    __builtin_amdgcn_sched_barrier(0)

__global__ __launch_bounds__(512, 2) void gemm_kernel(const bf16* __restrict__ xb,
                                                      const bf16* __restrict__ wb,
                                                      const float* __restrict__ bias,
                                                      float* __restrict__ out) {
  __shared__ bf16 lds[65536];  // 128 KiB: 2 buffers x (16K A + 16K B) elements

  const int tid = threadIdx.x;
  const int lane = tid & 63;
  const int w = tid >> 6;
  const int wr = w >> 2;  // 0..1  (M half, 128 rows)
  const int wc = w & 3;   // 0..3  (N quarter, 64 cols)

  // XCD mapping: xcd = gid&7 owns bm in [xcd*4, xcd*4+4), all bk.
  // 16 consecutive blocks on one XCD share bm -> A-panel L2-resident.
  const int gid = blockIdx.x;
  const int idx = gid >> 3;                   // 0..63
  const int bm = (gid & 7) * 4 + (idx >> 4);  // 32 M-tiles
  const int bk = idx & 15;                    // 16 K-tiles
  const long m0 = (long)bm * 256;
  const long k0 = (long)bk * 256;

  // ---- staging source decode (inverse swizzle), per-thread constants.
  const int browA = tid >> 3;                      // 0..63
  const int slotA = (tid & 7) ^ (browA & 7);
  const bf16* baseA = xb + (m0 + browA) * N_DIM + slotA * 8;
  const int u = tid & 255;
  const int wcb = tid >> 8;                        // 0..1
  const int browB = u >> 3;                        // 0..31
  const int slotB = (u & 7) ^ (browB & 7);
  const bf16* baseB = wb + (k0 + wcb * 64 + browB) * N_DIM + slotB * 8;

  // ---- ds_read fragment bases. Lane: row += (lane&15); k-slot = kk*4+(lane>>4);
  // x = (kk*4 + (lane>>4)) ^ (lane&7)  [row&7 == lane&7 for all frag rows].
  const int ln15 = lane & 15;
  const int x0 = (lane >> 4) ^ (lane & 7);
  int aoffk[2], boffk[2];
#pragma unroll
  for (int kk = 0; kk < 2; ++kk) {
    const int x = x0 ^ (kk << 2);
    aoffk[kk] = (wr * 128 + ln15) * 64 + x * 8;
    boffk[kk] = 16384 + (wc * 64 + ln15) * 64 + x * 8;
  }

  f32x4 acc[8][4] = {};
  bf16x8 afH0[4][2], afH1[4][2], bfA[2][2], bfB[2][2];

  auto STA = [&](int tt, int bsel, int h) {  // stage A-half h of tile tt
    const bf16* s = baseA + (long)(h * 64) * N_DIM + tt * 64;
    bf16* d = lds + bsel * 32768 + h * 4096 + (tid << 3);
    gload16(s, d);
    gload16(s + (long)128 * N_DIM, d + 8192);
  };
  auto STB = [&](int tt, int bsel, int h) {  // stage B-half h of tile tt
    const bf16* s = baseB + (long)(h * 32) * N_DIM + tt * 64;
    bf16* d = lds + bsel * 32768 + 16384 + wcb * 4096 + h * 2048 + (u << 3);
    gload16(s, d);
    gload16(s + (long)128 * N_DIM, d + 8192);
  };
  auto LDA = [&](bf16x8 (*dst)[2], int cb, int mh) {
#pragma unroll
    for (int mf = 0; mf < 4; ++mf)
#pragma unroll
      for (int kk = 0; kk < 2; ++kk)
        dst[mf][kk] = *reinterpret_cast<const bf16x8*>(
            lds + cb + aoffk[kk] + mh * 4096 + mf * 1024);
  };
  auto LDB = [&](bf16x8 (*dst)[2], int cb, int nh) {
#pragma unroll
    for (int nf = 0; nf < 2; ++nf)
#pragma unroll
      for (int kk = 0; kk < 2; ++kk)
        dst[nf][kk] = *reinterpret_cast<const bf16x8*>(
            lds + cb + boffk[kk] + nh * 2048 + nf * 1024);
  };
  auto MFMA_Q = [&](bf16x8 (*a4)[2], bf16x8 (*bf)[2], int mh, int nh) {
#pragma unroll
    for (int kk = 0; kk < 2; ++kk)
#pragma unroll
      for (int mf = 0; mf < 4; ++mf)
#pragma unroll
        for (int nf = 0; nf < 2; ++nf)
          acc[mh * 4 + mf][nh * 2 + nf] = __builtin_amdgcn_mfma_f32_16x16x32_bf16(
              a4[mf][kk], bf[nf][kk], acc[mh * 4 + mf][nh * 2 + nf], 0, 0, 0);
  };

  // Prologue: tile0 {Ah0,Bh0,Bh1,Ah1}, tile1 {Ah0,Bh0,Bh1} (7 pairs).
  // VM6 retires tile0's 8 loads; then prefetch ph0(0)'s frags.
  STA(0, 0, 0); STB(0, 0, 0); STB(0, 0, 1); STA(0, 0, 1);
  STA(1, 1, 0); STB(1, 1, 0); STB(1, 1, 1);
  VM6; BARRIER;
  LDA(afH0, 0, 0); LDB(bfA, 0, 0);

  auto TILE = [&](int t, int c) {
    const int cb = c * 32768;
    const int nb_ = (c ^ 1) * 32768;
    // ph0: MFMA(mh0,nh0)=afH0 x bfA; load bfB (Bh1, cur); stage Ah1(t+1)->other
    if (t + 1 < NT) STA(t + 1, c ^ 1, 1);
    BARRIER; LGKM0; SBAR;
    __builtin_amdgcn_s_setprio(1);
    LDB(bfB, cb, 1);
    MFMA_Q(afH0, bfA, 0, 0);
    __builtin_amdgcn_s_setprio(0);
    SBAR; BARRIER;
    // ph1: MFMA(mh0,nh1)=afH0 x bfB; load afH1 (Ah1, cur); stage Ah0(t+2)->cur
    if (t + 2 < NT) STA(t + 2, c, 0);
    BARRIER; LGKM0; SBAR;
    __builtin_amdgcn_s_setprio(1);
    LDA(afH1, cb, 1);
    MFMA_Q(afH0, bfB, 0, 1);
    __builtin_amdgcn_s_setprio(0);
    SBAR; BARRIER;
    // ph2: MFMA(mh1,nh0)=afH1 x bfA; stage Bh0(t+2)->cur
    if (t + 2 < NT) STB(t + 2, c, 0);
    BARRIER; LGKM0; SBAR;
    __builtin_amdgcn_s_setprio(1);
    MFMA_Q(afH1, bfA, 1, 0);
    __builtin_amdgcn_s_setprio(0);
    SBAR; BARRIER;
    // ph3: MFMA(mh1,nh1)=afH1 x bfB; prefetch t+1's afH0/bfA (other buf,
    // all landed per VM6 ledger); stage Bh1(t+2)->cur; counted wait.
    if (t + 2 < NT) STB(t + 2, c, 1);
    if (t < NT - 2) { VM6; } else { VM0; }
    BARRIER; LGKM0; SBAR;
    __builtin_amdgcn_s_setprio(1);
    if (t + 1 < NT) { LDA(afH0, nb_, 0); LDB(bfA, nb_, 0); }
    MFMA_Q(afH1, bfB, 1, 1);
    __builtin_amdgcn_s_setprio(0);
    SBAR; BARRIER;
  };

  for (int tp = 0; tp < NT / 2; ++tp) {
    TILE(2 * tp, 0);
    TILE(2 * tp + 1, 1);
  }

  // Epilogue. C/D: col = lane&15 (K-dim), row = (lane>>4)*4 + r (M-dim).
  // Non-temporal stores: out is write-once, keep xb/wb cached instead.
  const int ocol0 = (int)k0 + wc * 64 + ln15;
  const int orow0 = (int)m0 + wr * 128 + (lane >> 4) * 4;
#pragma unroll
  for (int ni = 0; ni < 4; ++ni) {
    const float bv = bias[ocol0 + ni * 16];
#pragma unroll
    for (int mi = 0; mi < 8; ++mi)
#pragma unroll
      for (int r = 0; r < 4; ++r)
        __builtin_nontemporal_store(
            acc[mi][ni][r] + bv,
            &out[(long)(orow0 + mi * 16 + r) * K_DIM + ocol0 + ni * 16]);
  }
}

// ---------------------------------------------------------------- launch
extern "C" void kernel_launch(void* const* d_in, const int* in_sizes, int n_in,
                              void* d_out, int out_size, void* d_ws, size_t ws_size,
                              hipStream_t stream) {
  const float* x      = (const float*)d_in[0];
  const int*   Wq     = (const int*)d_in[1];
  const float* scales = (const float*)d_in[2];
  const float* zeros  = (const float*)d_in[3];
  const int*   mask   = (const int*)d_in[4];
  const float* scale2 = (const float*)d_in[5];
  const float* bias   = (const float*)d_in[6];
  float* out = (float*)d_out;

  bf16* xb = (bf16*)d_ws;
  bf16* wb = (bf16*)((char*)d_ws + (size_t)M_DIM * N_DIM * 2);

  cvt_x_kernel<<<2048, 256, 0, stream>>>(x, xb);
  deq_w_kernel<<<2048, 256, 0, stream>>>(Wq, scales, zeros, mask, scale2, wb);

  // Grid: (M/256) * (K/256) = 32 * 16 = 512 blocks, 512 threads.
  gemm_kernel<<<512, 512, 0, stream>>>(xb, wb, bias, out);
}

// Round 10
// 282.442 us; speedup vs baseline: 1.1477x; 1.0162x over previous
//
#include <hip/hip_runtime.h>

// out[b,s,k] = sum_n x[b,s,n] * W[k,n] + bias[k]
// W[k,n] = (W_q[k,n] - zeros[k,n/64]) * scales[k,n/64] * scale2[k] * mask[k,n]
// M = B*S = 8192 (rows of x), N = 4096 (reduction), K = 4096 (out features).

#define M_DIM 8192
#define N_DIM 4096
#define K_DIM 4096
#define NT 64  // K-tiles of BK=64

typedef __bf16 bf16;
typedef __attribute__((ext_vector_type(8))) bf16 bf16x8;
typedef __attribute__((ext_vector_type(4))) float f32x4;
typedef __attribute__((ext_vector_type(4))) float f32x4v;   // nontemporal builtins
typedef __attribute__((ext_vector_type(4))) int   i32x4v;

// ---------------------------------------------------------------- pre-pass 1
__global__ __launch_bounds__(256) void cvt_x_kernel(const float* __restrict__ x,
                                                    bf16* __restrict__ xb) {
  const long total = (long)M_DIM * N_DIM / 8;
  const long stride = (long)gridDim.x * blockDim.x;
  for (long t = (long)blockIdx.x * blockDim.x + threadIdx.x; t < total; t += stride) {
    const long e = t * 8;
    const f32x4v v0 = __builtin_nontemporal_load(reinterpret_cast<const f32x4v*>(x + e));
    const f32x4v v1 = __builtin_nontemporal_load(reinterpret_cast<const f32x4v*>(x + e + 4));
    bf16x8 o;
    o[0] = (bf16)v0[0]; o[1] = (bf16)v0[1]; o[2] = (bf16)v0[2]; o[3] = (bf16)v0[3];
    o[4] = (bf16)v1[0]; o[5] = (bf16)v1[1]; o[6] = (bf16)v1[2]; o[7] = (bf16)v1[3];
    *reinterpret_cast<bf16x8*>(xb + e) = o;  // xb stays cached (GEMM re-reads)
  }
}

// ---------------------------------------------------------------- pre-pass 2
__global__ __launch_bounds__(256) void deq_w_kernel(const int* __restrict__ Wq,
                                                    const float* __restrict__ scales,
                                                    const float* __restrict__ zeros,
                                                    const int* __restrict__ mask,
                                                    const float* __restrict__ scale2,
                                                    bf16* __restrict__ wb) {
  const int total = K_DIM * (N_DIM / 8);
  const int stride = gridDim.x * blockDim.x;
  for (int t = blockIdx.x * blockDim.x + threadIdx.x; t < total; t += stride) {
    const int k = t >> 9;
    const int n0 = (t & 511) << 3;
    const int g = n0 >> 6;
    const float s = scales[(k << 6) + g] * scale2[k];
    const float z = zeros[(k << 6) + g];
    const long base = (long)k * N_DIM + n0;
    const i32x4v q0 = __builtin_nontemporal_load(reinterpret_cast<const i32x4v*>(Wq + base));
    const i32x4v q1 = __builtin_nontemporal_load(reinterpret_cast<const i32x4v*>(Wq + base + 4));
    const i32x4v m0 = __builtin_nontemporal_load(reinterpret_cast<const i32x4v*>(mask + base));
    const i32x4v m1 = __builtin_nontemporal_load(reinterpret_cast<const i32x4v*>(mask + base + 4));
    bf16x8 o;
    o[0] = (bf16)(((float)q0[0] - z) * s * (float)m0[0]);
    o[1] = (bf16)(((float)q0[1] - z) * s * (float)m0[1]);
    o[2] = (bf16)(((float)q0[2] - z) * s * (float)m0[2]);
    o[3] = (bf16)(((float)q0[3] - z) * s * (float)m0[3]);
    o[4] = (bf16)(((float)q1[0] - z) * s * (float)m1[0]);
    o[5] = (bf16)(((float)q1[1] - z) * s * (float)m1[1]);
    o[6] = (bf16)(((float)q1[2] - z) * s * (float)m1[2]);
    o[7] = (bf16)(((float)q1[3] - z) * s * (float)m1[3]);
    *reinterpret_cast<bf16x8*>(wb + base) = o;  // wb stays cached
  }
}

// ---------------------------------------------------------------- GEMM
// Round-9 skeleton (16x16x32, 0 conflicts, A-panel-resident XCD mapping,
// counted vmcnt(6), reg-frag double-buffering) with ONE barrier per phase
// (4/tile instead of 8).
//
// Single-barrier WAR rule: a wave's phase-p ds_reads drain at its p+1 LGKM0,
// which precedes barrier(p+2) for all waves -> stages may overwrite a region
// only >=2 phases after its unique read phase. Stage timing (all 3 phases
// after the region's read):
//   ph0: Ah1(t+1)->other  [other Ah1 read at ph1(t-1)]
//   ph2: Ah0(t+2)->cur    [cur Ah0 read at ph3(t-1) prefetch]
//        Bh0(t+2)->cur    [cur Bh0 read at ph3(t-1) prefetch]
//   ph3: Bh1(t+2)->cur    [cur Bh1 read at ph0(t)]
// FIFO ledger: at ph3 pre-VM6 outstanding=14; VM6 retires exactly tile t+1's
// 8 loads. Prologue (14 loads + VM6) reproduces steady state. Tail: VM0 at
// t >= NT-2.
//
// Frag sets: afH0/bfA prefetched at ph3(t-1) from other buf; bfB loaded ph0;
// afH1 loaded ph1. Each phase's MFMA consumes frags loaded >=1 phase earlier.
__device__ inline void gload16(const bf16* g, bf16* l) {
  __builtin_amdgcn_global_load_lds(
      (const __attribute__((address_space(1))) void*)g,
      (__attribute__((address_space(3))) void*)l, 16, 0, 0);
}

#define BARRIER asm volatile("s_barrier" ::: "memory")
#define LGKM0   asm volatile("s_waitcnt lgkmcnt(0)" ::: "memory")
#define VM6     asm volatile("s_waitcnt vmcnt(6)" ::: "memory")
#define VM0     asm volatile("s_waitcnt vmcnt(0)" ::: "memory")
#define SBAR    __builtin_amdgcn_sched_barrier(0)

__global__ __launch_bounds__(512, 2) void gemm_kernel(const bf16* __restrict__ xb,
                                                      const bf16* __restrict__ wb,
                                                      const float* __restrict__ bias,
                                                      float* __restrict__ out) {
  __shared__ bf16 lds[65536];  // 128 KiB: 2 buffers x (16K A + 16K B) elements

  const int tid = threadIdx.x;
  const int lane = tid & 63;
  const int w = tid >> 6;
  const int wr = w >> 2;  // 0..1  (M half, 128 rows)
  const int wc = w & 3;   // 0..3  (N quarter, 64 cols)

  // XCD mapping: xcd = gid&7 owns bm in [xcd*4, xcd*4+4), all bk.
  // 16 consecutive blocks on one XCD share bm -> A-panel L2-resident.
  const int gid = blockIdx.x;
  const int idx = gid >> 3;                   // 0..63
  const int bm = (gid & 7) * 4 + (idx >> 4);  // 32 M-tiles
  const int bk = idx & 15;                    // 16 K-tiles
  const long m0 = (long)bm * 256;
  const long k0 = (long)bk * 256;

  // ---- staging source decode (inverse swizzle), per-thread constants.
  const int browA = tid >> 3;                      // 0..63
  const int slotA = (tid & 7) ^ (browA & 7);
  const bf16* baseA = xb + (m0 + browA) * N_DIM + slotA * 8;
  const int u = tid & 255;
  const int wcb = tid >> 8;                        // 0..1
  const int browB = u >> 3;                        // 0..31
  const int slotB = (u & 7) ^ (browB & 7);
  const bf16* baseB = wb + (k0 + wcb * 64 + browB) * N_DIM + slotB * 8;

  // ---- ds_read fragment bases. Lane: row += (lane&15); k-slot = kk*4+(lane>>4);
  // x = (kk*4 + (lane>>4)) ^ (lane&7)  [row&7 == lane&7 for all frag rows].
  const int ln15 = lane & 15;
  const int x0 = (lane >> 4) ^ (lane & 7);
  int aoffk[2], boffk[2];
#pragma unroll
  for (int kk = 0; kk < 2; ++kk) {
    const int x = x0 ^ (kk << 2);
    aoffk[kk] = (wr * 128 + ln15) * 64 + x * 8;
    boffk[kk] = 16384 + (wc * 64 + ln15) * 64 + x * 8;
  }

  f32x4 acc[8][4] = {};
  bf16x8 afH0[4][2], afH1[4][2], bfA[2][2], bfB[2][2];

  auto STA = [&](int tt, int bsel, int h) {  // stage A-half h of tile tt
    const bf16* s = baseA + (long)(h * 64) * N_DIM + tt * 64;
    bf16* d = lds + bsel * 32768 + h * 4096 + (tid << 3);
    gload16(s, d);
    gload16(s + (long)128 * N_DIM, d + 8192);
  };
  auto STB = [&](int tt, int bsel, int h) {  // stage B-half h of tile tt
    const bf16* s = baseB + (long)(h * 32) * N_DIM + tt * 64;
    bf16* d = lds + bsel * 32768 + 16384 + wcb * 4096 + h * 2048 + (u << 3);
    gload16(s, d);
    gload16(s + (long)128 * N_DIM, d + 8192);
  };
  auto LDA = [&](bf16x8 (*dst)[2], int cb, int mh) {
#pragma unroll
    for (int mf = 0; mf < 4; ++mf)
#pragma unroll
      for (int kk = 0; kk < 2; ++kk)
        dst[mf][kk] = *reinterpret_cast<const bf16x8*>(
            lds + cb + aoffk[kk] + mh * 4096 + mf * 1024);
  };
  auto LDB = [&](bf16x8 (*dst)[2], int cb, int nh) {
#pragma unroll
    for (int nf = 0; nf < 2; ++nf)
#pragma unroll
      for (int kk = 0; kk < 2; ++kk)
        dst[nf][kk] = *reinterpret_cast<const bf16x8*>(
            lds + cb + boffk[kk] + nh * 2048 + nf * 1024);
  };
  auto MFMA_Q = [&](bf16x8 (*a4)[2], bf16x8 (*bf)[2], int mh, int nh) {
#pragma unroll
    for (int kk = 0; kk < 2; ++kk)
#pragma unroll
      for (int mf = 0; mf < 4; ++mf)
#pragma unroll
        for (int nf = 0; nf < 2; ++nf)
          acc[mh * 4 + mf][nh * 2 + nf] = __builtin_amdgcn_mfma_f32_16x16x32_bf16(
              a4[mf][kk], bf[nf][kk], acc[mh * 4 + mf][nh * 2 + nf], 0, 0, 0);
  };

  // Prologue: tile0 {Ah0,Bh0,Bh1,Ah1}, tile1 {Ah0,Bh0,Bh1} (14 loads).
  // VM6 retires tile0's 8; then prefetch ph0(0)'s frags from buf0.
  STA(0, 0, 0); STB(0, 0, 0); STB(0, 0, 1); STA(0, 0, 1);
  STA(1, 1, 0); STB(1, 1, 0); STB(1, 1, 1);
  VM6; BARRIER;
  LDA(afH0, 0, 0); LDB(bfA, 0, 0);

  auto TILE = [&](int t, int c) {
    const int cb = c * 32768;
    const int ob = (c ^ 1) * 32768;
    // ph0: stage Ah1(t+1)->other | MFMA(mh0,nh0) + load bfB (Bh1 cur)
    if (t + 1 < NT) STA(t + 1, c ^ 1, 1);
    BARRIER; LGKM0; SBAR;
    __builtin_amdgcn_s_setprio(1);
    LDB(bfB, cb, 1);
    MFMA_Q(afH0, bfA, 0, 0);
    __builtin_amdgcn_s_setprio(0);
    // ph1: MFMA(mh0,nh1) + load afH1 (Ah1 cur)
    BARRIER; LGKM0; SBAR;
    __builtin_amdgcn_s_setprio(1);
    LDA(afH1, cb, 1);
    MFMA_Q(afH0, bfB, 0, 1);
    __builtin_amdgcn_s_setprio(0);
    // ph2: stage Ah0(t+2)+Bh0(t+2)->cur | MFMA(mh1,nh0)
    if (t + 2 < NT) { STA(t + 2, c, 0); STB(t + 2, c, 0); }
    BARRIER; LGKM0; SBAR;
    __builtin_amdgcn_s_setprio(1);
    MFMA_Q(afH1, bfA, 1, 0);
    __builtin_amdgcn_s_setprio(0);
    // ph3: stage Bh1(t+2)->cur; counted VM6 (retires all of tile t+1) |
    //      MFMA(mh1,nh1) + prefetch t+1's afH0/bfA from other buf
    if (t + 2 < NT) STB(t + 2, c, 1);
    if (t < NT - 2) { VM6; } else { VM0; }
    BARRIER; LGKM0; SBAR;
    __builtin_amdgcn_s_setprio(1);
    if (t + 1 < NT) { LDA(afH0, ob, 0); LDB(bfA, ob, 0); }
    MFMA_Q(afH1, bfB, 1, 1);
    __builtin_amdgcn_s_setprio(0);
  };

  for (int tp = 0; tp < NT / 2; ++tp) {
    TILE(2 * tp, 0);
    TILE(2 * tp + 1, 1);
  }

  // Epilogue. C/D: col = lane&15 (K-dim), row = (lane>>4)*4 + r (M-dim).
  // Non-temporal stores: out is write-once, keep xb/wb cached instead.
  const int ocol0 = (int)k0 + wc * 64 + ln15;
  const int orow0 = (int)m0 + wr * 128 + (lane >> 4) * 4;
#pragma unroll
  for (int ni = 0; ni < 4; ++ni) {
    const float bv = bias[ocol0 + ni * 16];
#pragma unroll
    for (int mi = 0; mi < 8; ++mi)
#pragma unroll
      for (int r = 0; r < 4; ++r)
        __builtin_nontemporal_store(
            acc[mi][ni][r] + bv,
            &out[(long)(orow0 + mi * 16 + r) * K_DIM + ocol0 + ni * 16]);
  }
}

// ---------------------------------------------------------------- launch
extern "C" void kernel_launch(void* const* d_in, const int* in_sizes, int n_in,
                              void* d_out, int out_size, void* d_ws, size_t ws_size,
                              hipStream_t stream) {
  const float* x      = (const float*)d_in[0];
  const int*   Wq     = (const int*)d_in[1];
  const float* scales = (const float*)d_in[2];
  const float* zeros  = (const float*)d_in[3];
  const int*   mask   = (const int*)d_in[4];
  const float* scale2 = (const float*)d_in[5];
  const float* bias   = (const float*)d_in[6];
  float* out = (float*)d_out;

  bf16* xb = (bf16*)d_ws;
  bf16* wb = (bf16*)((char*)d_ws + (size_t)M_DIM * N_DIM * 2);

  cvt_x_kernel<<<2048, 256, 0, stream>>>(x, xb);
  deq_w_kernel<<<2048, 256, 0, stream>>>(Wq, scales, zeros, mask, scale2, wb);

  // Grid: (M/256) * (K/256) = 32 * 16 = 512 blocks, 512 threads.
  gemm_kernel<<<512, 512, 0, stream>>>(xb, wb, bias, out);
}

// Round 11
// 279.440 us; speedup vs baseline: 1.1601x; 1.0107x over previous
//
#include <hip/hip_runtime.h>

// out[b,s,k] = sum_n x[b,s,n] * W[k,n] + bias[k]
// W[k,n] = (W_q[k,n] - zeros[k,n/64]) * scales[k,n/64] * scale2[k] * mask[k,n]
// M = B*S = 8192 (rows of x), N = 4096 (reduction), K = 4096 (out features).

#define M_DIM 8192
#define N_DIM 4096
#define K_DIM 4096
#define NT 64  // K-tiles of BK=64

typedef __bf16 bf16;
typedef __attribute__((ext_vector_type(8))) bf16 bf16x8;
typedef __attribute__((ext_vector_type(4))) float f32x4;
typedef __attribute__((ext_vector_type(4))) float f32x4v;   // nontemporal builtins
typedef __attribute__((ext_vector_type(4))) int   i32x4v;

// ---------------------------------------------------------------- pre-pass 1
__global__ __launch_bounds__(256) void cvt_x_kernel(const float* __restrict__ x,
                                                    bf16* __restrict__ xb) {
  const long total = (long)M_DIM * N_DIM / 8;
  const long stride = (long)gridDim.x * blockDim.x;
  for (long t = (long)blockIdx.x * blockDim.x + threadIdx.x; t < total; t += stride) {
    const long e = t * 8;
    const f32x4v v0 = __builtin_nontemporal_load(reinterpret_cast<const f32x4v*>(x + e));
    const f32x4v v1 = __builtin_nontemporal_load(reinterpret_cast<const f32x4v*>(x + e + 4));
    bf16x8 o;
    o[0] = (bf16)v0[0]; o[1] = (bf16)v0[1]; o[2] = (bf16)v0[2]; o[3] = (bf16)v0[3];
    o[4] = (bf16)v1[0]; o[5] = (bf16)v1[1]; o[6] = (bf16)v1[2]; o[7] = (bf16)v1[3];
    *reinterpret_cast<bf16x8*>(xb + e) = o;  // xb stays cached (GEMM re-reads)
  }
}

// ---------------------------------------------------------------- pre-pass 2
__global__ __launch_bounds__(256) void deq_w_kernel(const int* __restrict__ Wq,
                                                    const float* __restrict__ scales,
                                                    const float* __restrict__ zeros,
                                                    const int* __restrict__ mask,
                                                    const float* __restrict__ scale2,
                                                    bf16* __restrict__ wb) {
  const int total = K_DIM * (N_DIM / 8);
  const int stride = gridDim.x * blockDim.x;
  for (int t = blockIdx.x * blockDim.x + threadIdx.x; t < total; t += stride) {
    const int k = t >> 9;
    const int n0 = (t & 511) << 3;
    const int g = n0 >> 6;
    const float s = scales[(k << 6) + g] * scale2[k];
    const float z = zeros[(k << 6) + g];
    const long base = (long)k * N_DIM + n0;
    const i32x4v q0 = __builtin_nontemporal_load(reinterpret_cast<const i32x4v*>(Wq + base));
    const i32x4v q1 = __builtin_nontemporal_load(reinterpret_cast<const i32x4v*>(Wq + base + 4));
    const i32x4v m0 = __builtin_nontemporal_load(reinterpret_cast<const i32x4v*>(mask + base));
    const i32x4v m1 = __builtin_nontemporal_load(reinterpret_cast<const i32x4v*>(mask + base + 4));
    bf16x8 o;
    o[0] = (bf16)(((float)q0[0] - z) * s * (float)m0[0]);
    o[1] = (bf16)(((float)q0[1] - z) * s * (float)m0[1]);
    o[2] = (bf16)(((float)q0[2] - z) * s * (float)m0[2]);
    o[3] = (bf16)(((float)q0[3] - z) * s * (float)m0[3]);
    o[4] = (bf16)(((float)q1[0] - z) * s * (float)m1[0]);
    o[5] = (bf16)(((float)q1[1] - z) * s * (float)m1[1]);
    o[6] = (bf16)(((float)q1[2] - z) * s * (float)m1[2]);
    o[7] = (bf16)(((float)q1[3] - z) * s * (float)m1[3]);
    *reinterpret_cast<bf16x8*>(wb + base) = o;  // wb stays cached
  }
}

// ---------------------------------------------------------------- GEMM
// 2 phases per K-tile (2 barriers, 2 lgkm-drains, 2 counted vmcnt). Each
// phase = 32 MFMA. LGKM0 placed BEFORE the barrier: reader's drain formally
// precedes any wave's post-barrier stage (WAR airtight), and the drain
// overlaps the barrier wait.
//
// Frags: afH0/bfA/bfB prefetched during PH1(s-1) from buf(s); afH1 loaded
// during PH0(s). PH0 computes mh0 x {nh0,nh1}; PH1 computes mh1 x {nh0,nh1}.
// In PH1, bfA/bfB prefetch is ordered AFTER the MFMAs consuming them (reg WAR).
//
// Stages: PH0(s): Ah1(s+1)->other buf   [region read as afH1(s-1) at PH0(s-1)]
//         PH1(s): Ah0/Bh0/Bh1(s+2)->cur [regions read by prefetch at PH1(s-1)]
// All overwrites >=2 phases after the region's unique read phase.
//
// FIFO vmcnt ledger (steady): PH0 outstanding 8 (+2 stage) -> VM8 retires
// Ah1(s); PH1 outstanding 8 (+6 stage) -> VM8 retires Ah0/Bh0/Bh1(s+1).
// Tail: PH0(NT-1) VM0; PH1(NT-2) VM2; PH1(NT-1) skips prefetch.
// Prologue: 14 loads, VM6 retires tile0's 8.
__device__ inline void gload16(const bf16* g, bf16* l) {
  __builtin_amdgcn_global_load_lds(
      (const __attribute__((address_space(1))) void*)g,
      (__attribute__((address_space(3))) void*)l, 16, 0, 0);
}

#define BARRIER asm volatile("s_barrier" ::: "memory")
#define LGKM0   asm volatile("s_waitcnt lgkmcnt(0)" ::: "memory")
#define VM8     asm volatile("s_waitcnt vmcnt(8)" ::: "memory")
#define VM6     asm volatile("s_waitcnt vmcnt(6)" ::: "memory")
#define VM2     asm volatile("s_waitcnt vmcnt(2)" ::: "memory")
#define VM0     asm volatile("s_waitcnt vmcnt(0)" ::: "memory")
#define SBAR    __builtin_amdgcn_sched_barrier(0)

__global__ __launch_bounds__(512, 2) void gemm_kernel(const bf16* __restrict__ xb,
                                                      const bf16* __restrict__ wb,
                                                      const float* __restrict__ bias,
                                                      float* __restrict__ out) {
  __shared__ bf16 lds[65536];  // 128 KiB: 2 buffers x (16K A + 16K B) elements

  const int tid = threadIdx.x;
  const int lane = tid & 63;
  const int w = tid >> 6;
  const int wr = w >> 2;  // 0..1  (M half, 128 rows)
  const int wc = w & 3;   // 0..3  (N quarter, 64 cols)

  // XCD mapping: xcd = gid&7 owns bm in [xcd*4, xcd*4+4), all bk.
  // 16 consecutive blocks on one XCD share bm -> A-panel L2-resident.
  const int gid = blockIdx.x;
  const int idx = gid >> 3;                   // 0..63
  const int bm = (gid & 7) * 4 + (idx >> 4);  // 32 M-tiles
  const int bk = idx & 15;                    // 16 K-tiles
  const long m0 = (long)bm * 256;
  const long k0 = (long)bk * 256;

  // ---- staging source decode (inverse swizzle), per-thread constants.
  const int browA = tid >> 3;                      // 0..63
  const int slotA = (tid & 7) ^ (browA & 7);
  const bf16* baseA = xb + (m0 + browA) * N_DIM + slotA * 8;
  const int u = tid & 255;
  const int wcb = tid >> 8;                        // 0..1
  const int browB = u >> 3;                        // 0..31
  const int slotB = (u & 7) ^ (browB & 7);
  const bf16* baseB = wb + (k0 + wcb * 64 + browB) * N_DIM + slotB * 8;

  // ---- ds_read fragment bases. Lane: row += (lane&15); k-slot = kk*4+(lane>>4);
  // x = (kk*4 + (lane>>4)) ^ (lane&7)  [row&7 == lane&7 for all frag rows].
  const int ln15 = lane & 15;
  const int x0 = (lane >> 4) ^ (lane & 7);
  int aoffk[2], boffk[2];
#pragma unroll
  for (int kk = 0; kk < 2; ++kk) {
    const int x = x0 ^ (kk << 2);
    aoffk[kk] = (wr * 128 + ln15) * 64 + x * 8;
    boffk[kk] = 16384 + (wc * 64 + ln15) * 64 + x * 8;
  }

  f32x4 acc[8][4] = {};
  bf16x8 afH0[4][2], afH1[4][2], bfA[2][2], bfB[2][2];

  auto STA = [&](int tt, int bsel, int h) {  // stage A-half h of tile tt
    const bf16* s = baseA + (long)(h * 64) * N_DIM + tt * 64;
    bf16* d = lds + bsel * 32768 + h * 4096 + (tid << 3);
    gload16(s, d);
    gload16(s + (long)128 * N_DIM, d + 8192);
  };
  auto STB = [&](int tt, int bsel, int h) {  // stage B-half h of tile tt
    const bf16* s = baseB + (long)(h * 32) * N_DIM + tt * 64;
    bf16* d = lds + bsel * 32768 + 16384 + wcb * 4096 + h * 2048 + (u << 3);
    gload16(s, d);
    gload16(s + (long)128 * N_DIM, d + 8192);
  };
  auto LDA = [&](bf16x8 (*dst)[2], int cb, int mh) {
#pragma unroll
    for (int mf = 0; mf < 4; ++mf)
#pragma unroll
      for (int kk = 0; kk < 2; ++kk)
        dst[mf][kk] = *reinterpret_cast<const bf16x8*>(
            lds + cb + aoffk[kk] + mh * 4096 + mf * 1024);
  };
  auto LDB1 = [&](bf16x8* dst, int cb, int nh, int nf) {  // one nf column
#pragma unroll
    for (int kk = 0; kk < 2; ++kk)
      dst[kk] = *reinterpret_cast<const bf16x8*>(
          lds + cb + boffk[kk] + nh * 2048 + nf * 1024);
  };
  auto MFMA_Q = [&](bf16x8 (*a4)[2], bf16x8 (*bf)[2], int mh, int nh) {
#pragma unroll
    for (int kk = 0; kk < 2; ++kk)
#pragma unroll
      for (int mf = 0; mf < 4; ++mf)
#pragma unroll
        for (int nf = 0; nf < 2; ++nf)
          acc[mh * 4 + mf][nh * 2 + nf] = __builtin_amdgcn_mfma_f32_16x16x32_bf16(
              a4[mf][kk], bf[nf][kk], acc[mh * 4 + mf][nh * 2 + nf], 0, 0, 0);
  };

  // Prologue: tile0 {Ah0,Bh0,Bh1,Ah1}, tile1 {Ah0,Bh0,Bh1} (14 loads).
  // VM6 retires tile0's 8; prefetch tile0's afH0/bfA/bfB from buf0.
  STA(0, 0, 0); STB(0, 0, 0); STB(0, 0, 1); STA(0, 0, 1);
  STA(1, 1, 0); STB(1, 1, 0); STB(1, 1, 1);
  VM6; BARRIER;
  LDA(afH0, 0, 0);
  LDB1(bfA[0], 0, 0, 0); LDB1(bfA[1], 0, 0, 1);
  LDB1(bfB[0], 0, 1, 0); LDB1(bfB[1], 0, 1, 1);

  for (int s = 0; s < NT; ++s) {
    const int c = s & 1;
    const int cb = c * 32768;
    const int ob = (c ^ 1) * 32768;
    // ---- PH0: MFMA mh0 x {nh0,nh1} (afH0 x bfA/bfB) + load afH1(cur);
    //      stage Ah1(s+1)->other.
    if (s + 1 < NT) { STA(s + 1, c ^ 1, 1); VM8; } else { VM0; }
    LGKM0;            // drains PH1(s-1)'s prefetch reads (afH0/bfA/bfB)
    BARRIER; SBAR;
    __builtin_amdgcn_s_setprio(1);
    LDA(afH1, cb, 1);
    MFMA_Q(afH0, bfA, 0, 0);
    MFMA_Q(afH0, bfB, 0, 1);
    __builtin_amdgcn_s_setprio(0);
    // ---- PH1: MFMA mh1 x {nh0,nh1} (afH1 x bfA/bfB) + prefetch next tile's
    //      afH0/bfA/bfB from other buf; stage Ah0/Bh0/Bh1(s+2)->cur.
    if (s + 2 < NT) { STA(s + 2, c, 0); STB(s + 2, c, 0); STB(s + 2, c, 1); VM8; }
    else if (s + 1 < NT) { VM2; }
    LGKM0;            // drains PH0's LDA afH1
    BARRIER; SBAR;
    __builtin_amdgcn_s_setprio(1);
    if (s + 1 < NT) LDA(afH0, ob, 0);          // no reg conflict with PH1 MFMA
    MFMA_Q(afH1, bfA, 1, 0);
    if (s + 1 < NT) { LDB1(bfA[0], ob, 0, 0); LDB1(bfA[1], ob, 0, 1); }  // WAR: after consume
    MFMA_Q(afH1, bfB, 1, 1);
    if (s + 1 < NT) { LDB1(bfB[0], ob, 1, 0); LDB1(bfB[1], ob, 1, 1); }
    __builtin_amdgcn_s_setprio(0);
  }

  // Epilogue. C/D: col = lane&15 (K-dim), row = (lane>>4)*4 + r (M-dim).
  // Non-temporal stores: out is write-once, keep xb/wb cached instead.
  const int ocol0 = (int)k0 + wc * 64 + ln15;
  const int orow0 = (int)m0 + wr * 128 + (lane >> 4) * 4;
#pragma unroll
  for (int ni = 0; ni < 4; ++ni) {
    const float bv = bias[ocol0 + ni * 16];
#pragma unroll
    for (int mi = 0; mi < 8; ++mi)
#pragma unroll
      for (int r = 0; r < 4; ++r)
        __builtin_nontemporal_store(
            acc[mi][ni][r] + bv,
            &out[(long)(orow0 + mi * 16 + r) * K_DIM + ocol0 + ni * 16]);
  }
}

// ---------------------------------------------------------------- launch
extern "C" void kernel_launch(void* const* d_in, const int* in_sizes, int n_in,
                              void* d_out, int out_size, void* d_ws, size_t ws_size,
                              hipStream_t stream) {
  const float* x      = (const float*)d_in[0];
  const int*   Wq     = (const int*)d_in[1];
  const float* scales = (const float*)d_in[2];
  const float* zeros  = (const float*)d_in[3];
  const int*   mask   = (const int*)d_in[4];
  const float* scale2 = (const float*)d_in[5];
  const float* bias   = (const float*)d_in[6];
  float* out = (float*)d_out;

  bf16* xb = (bf16*)d_ws;
  bf16* wb = (bf16*)((char*)d_ws + (size_t)M_DIM * N_DIM * 2);

  cvt_x_kernel<<<2048, 256, 0, stream>>>(x, xb);
  deq_w_kernel<<<2048, 256, 0, stream>>>(Wq, scales, zeros, mask, scale2, wb);

  // Grid: (M/256) * (K/256) = 32 * 16 = 512 blocks, 512 threads.
  gemm_kernel<<<512, 512, 0, stream>>>(xb, wb, bias, out);
}